// Round 1
// baseline (254.261 us; speedup 1.0000x reference)
//
#include <hip/hip_runtime.h>
#include <math.h>

#define XD 32
#define HD 128

typedef short bhalf8 __attribute__((ext_vector_type(8)));
typedef float f32x16 __attribute__((ext_vector_type(16)));
typedef int v2i __attribute__((ext_vector_type(2)));

static __device__ __forceinline__ short f2bf_rne(float f){
  union { float f; unsigned u; } v; v.f = f;
  unsigned r = v.u + 0x7FFFu + ((v.u >> 16) & 1u);
  return (short)(r >> 16);
}

// truncating f32->bf16 pair pack (cheap; tolerance has 100x margin)
static __device__ __forceinline__ int packbf(float a, float b){
  union { float f; unsigned u; } x, y; x.f = a; y.f = b;
  return (int)((x.u >> 16) | (y.u & 0xFFFF0000u));
}

static __device__ __forceinline__ bhalf8 mk_frag(int d0,int d1,int d2,int d3){
  union { int i[4]; bhalf8 v; } u;
  u.i[0]=d0; u.i[1]=d1; u.i[2]=d2; u.i[3]=d3;
  return u.v;
}

// exchange: x' = {x.lo32lanes, y.lo32lanes}, y' = {x.hi32lanes, y.hi32lanes}
static __device__ __forceinline__ void plswap(int &x, int &y){
#if __has_builtin(__builtin_amdgcn_permlane32_swap)
  v2i r = __builtin_amdgcn_permlane32_swap(x, y, false, false);
  x = r[0]; y = r[1];
#else
  unsigned lane = threadIdx.x & 63u;
  int sx = __shfl_xor(x, 32, 64);
  int sy = __shfl_xor(y, 32, 64);
  int nx = (lane < 32) ? x : sy;
  int ny = (lane < 32) ? sx : y;
  x = nx; y = ny;
#endif
}

// Convert one 32x32 C tile (f32, relu applied here) into two K=16 B-frags
// for the next layer. C: feat=(r&3)+8*(r>>2)+4*half, batch=lane&31.
// B: k=(half)*8+j, col=lane&31.  Value at (half',j) comes from C reg
// r=(f&3)+4*(f>>3), source-half h=(f>>2)&1 with f = 16*ktB + 8*half' + j.
static __device__ __forceinline__ void c2b(const f32x16 &c, bhalf8 &bA, bhalf8 &bB){
  float r[16];
#pragma unroll
  for (int q=0;q<16;++q) r[q] = fmaxf(c[q], 0.0f);
  int p01 = packbf(r[0], r[1]);
  int p23 = packbf(r[2], r[3]);
  int p45 = packbf(r[4], r[5]);
  int p67 = packbf(r[6], r[7]);
  int p89 = packbf(r[8], r[9]);
  int pab = packbf(r[10], r[11]);
  int pcd = packbf(r[12], r[13]);
  int pef = packbf(r[14], r[15]);
  int d0 = p01, d2 = p45; plswap(d0, d2);
  int d1 = p23, d3 = p67; plswap(d1, d3);
  int e0 = p89, e2 = pcd; plswap(e0, e2);
  int e1 = pab, e3 = pef; plswap(e1, e3);
  bA = mk_frag(d0, d1, d2, d3);
  bB = mk_frag(e0, e1, e2, e3);
}

// bias/wf gather in C-layout: element rg*4+q <- p[rg*8 + half*4 + q]
static __device__ __forceinline__ f32x16 load_bias16(const float* __restrict__ p, int half){
  f32x16 bv;
#pragma unroll
  for (int rg=0; rg<4; ++rg){
    const float4 t = *(const float4*)(p + rg*8 + half*4);
    bv[rg*4+0]=t.x; bv[rg*4+1]=t.y; bv[rg*4+2]=t.z; bv[rg*4+3]=t.w;
  }
  return bv;
}

// ---- prep: pack Wi (with z-column folded into slot k==i) into A-frag order ----
// frag index b = i*8 + fo*2 + kt ; element: lane l holds row=fo*32+(l&31),
// k = kt*16 + (l>>5)*8 + j
__global__ void prep_pack(const float* __restrict__ Wi, short* __restrict__ wip){
  int b = (int)blockIdx.x;            // 256 blocks
  int i = b >> 3;
  int fo = (b >> 1) & 3;
  int kt = b & 1;
  int l = (int)threadIdx.x;           // 64 threads
  int row = fo*32 + (l & 31);
  int h = l >> 5;
  union { short s[8]; bhalf8 v; } u;
#pragma unroll
  for (int j = 0; j < 8; ++j){
    int k = kt*16 + h*8 + j;
    int src = (k == i) ? XD : k;      // z column replaces dead diagonal slot
    float v = Wi[((size_t)i*HD + row)*(XD+1) + src];
    u.s[j] = f2bf_rne(v);
  }
  *(bhalf8*)&wip[((size_t)b*64 + l)*8] = u.v;
}

__global__ void prep_mt(const float* __restrict__ M, float* __restrict__ Mt){
  int t = (int)threadIdx.x;
  if (t < 1024){
    int i = t >> 5, k = t & 31;
    Mt[i*32 + k] = M[k*32 + i];
  }
}

// ---- main kernel: 256 WGs x 256 threads; wave owns 64 rows ----
__global__ __launch_bounds__(256, 1)
void genkern(const float* __restrict__ x, const float* __restrict__ z,
             const float* __restrict__ bi, const float* __restrict__ wf,
             const float* __restrict__ bf, const float* __restrict__ W1,
             const float* __restrict__ b1, const float* __restrict__ W2,
             const float* __restrict__ b2,
             const short* __restrict__ wip, const float* __restrict__ Mt,
             float* __restrict__ out)
{
  extern __shared__ char smem[];
  short* wlds = (short*)smem;                 // 64 A-frags (W1 then W2): 64KB
  float* olds = (float*)(smem + 65536);       // out state: 4 waves * 64 rows * 36 f32

  const int tid  = (int)threadIdx.x;
  const int lane = tid & 63;
  const int wv   = tid >> 6;
  const int half = lane >> 5;
  const int col  = lane & 31;

  // preload W1/W2 as A-frags into LDS (frag f: fo=f>>3&3, kt=f&7; W2 at f>=32)
  for (int pass = 0; pass < 16; ++pass){
    int f = pass*4 + wv;
    const float* W = (f < 32) ? W1 : W2;
    int fl = f & 31;
    int fo = fl >> 3, kt = fl & 7;
    const float* src = W + (size_t)(fo*32 + col)*HD + kt*16 + half*8;
    float4 aa = *(const float4*)src;
    float4 bb = *(const float4*)(src + 4);
    union { short s[8]; bhalf8 v; } u;
    u.s[0]=f2bf_rne(aa.x); u.s[1]=f2bf_rne(aa.y); u.s[2]=f2bf_rne(aa.z); u.s[3]=f2bf_rne(aa.w);
    u.s[4]=f2bf_rne(bb.x); u.s[5]=f2bf_rne(bb.y); u.s[6]=f2bf_rne(bb.z); u.s[7]=f2bf_rne(bb.w);
    *(bhalf8*)&wlds[((size_t)f*64 + lane)*8] = u.v;
  }

  const int rbase = (int)blockIdx.x * 256 + wv * 64;
  float* ow = olds + wv * (64*36);
  for (int idx = lane; idx < 64*32; idx += 64){
    int r = idx >> 5, c = idx & 31;
    ow[r*36 + c] = x[(size_t)(rbase + r)*XD + c];
  }
  __syncthreads();

  for (int i = 0; i < XD; ++i){
    // per-step Wi A-frags: global (L2-hot) -> VGPR, bypass LDS
    bhalf8 wif[4][2];
#pragma unroll
    for (int fo=0; fo<4; ++fo)
#pragma unroll
      for (int kt=0; kt<2; ++kt)
        wif[fo][kt] = *(const bhalf8*)&wip[(((size_t)i*8 + fo*2 + kt)*64 + lane)*8];

    // M column i (broadcast reads)
    float mtv[2][8];
#pragma unroll
    for (int kt=0; kt<2; ++kt){
      const float* mp = Mt + i*32 + kt*16 + half*8;
      float4 a  = *(const float4*)mp;
      float4 b4 = *(const float4*)(mp+4);
      mtv[kt][0]=a.x;  mtv[kt][1]=a.y;  mtv[kt][2]=a.z;  mtv[kt][3]=a.w;
      mtv[kt][4]=b4.x; mtv[kt][5]=b4.y; mtv[kt][6]=b4.z; mtv[kt][7]=b4.w;
    }

    float zv[2];
#pragma unroll
    for (int bt=0; bt<2; ++bt)
      zv[bt] = z[(size_t)(rbase + bt*32 + col)*XD + i];

    // build x_masked B-frags from out-state (z injected at k==i)
    bhalf8 xb[2][2];
#pragma unroll
    for (int bt=0; bt<2; ++bt){
      const float* orow = ow + (bt*32 + col)*36;
#pragma unroll
      for (int kt=0; kt<2; ++kt){
        const float4 o0 = *(const float4*)(orow + kt*16 + half*8);
        const float4 o1 = *(const float4*)(orow + kt*16 + half*8 + 4);
        float xv[8] = {o0.x,o0.y,o0.z,o0.w,o1.x,o1.y,o1.z,o1.w};
        int d[4];
#pragma unroll
        for (int p=0;p<4;++p){
          int kb = kt*16 + half*8 + 2*p;
          float v0 = xv[2*p]   * mtv[kt][2*p];
          float v1 = xv[2*p+1] * mtv[kt][2*p+1];
          v0 = (kb   == i) ? zv[bt] : v0;
          v1 = (kb+1 == i) ? zv[bt] : v1;
          d[p] = packbf(v0, v1);
        }
        xb[bt][kt] = mk_frag(d[0],d[1],d[2],d[3]);
      }
    }

    // input layer: D[feat,batch] = Wi_i * xm^T + bi
    f32x16 acc[4][2];
#pragma unroll
    for (int fo=0; fo<4; ++fo){
      f32x16 bv = load_bias16(bi + (size_t)i*HD + fo*32, half);
      acc[fo][0] = bv; acc[fo][1] = bv;
    }
#pragma unroll
    for (int kt=0; kt<2; ++kt)
#pragma unroll
      for (int fo=0; fo<4; ++fo)
#pragma unroll
        for (int bt=0; bt<2; ++bt)
          acc[fo][bt] = __builtin_amdgcn_mfma_f32_32x32x16_bf16(wif[fo][kt], xb[bt][kt], acc[fo][bt], 0,0,0);

    // relu + in-register relayout -> B-frags for layer 1
    bhalf8 hb[2][8];
#pragma unroll
    for (int fo=0; fo<4; ++fo)
#pragma unroll
      for (int bt=0; bt<2; ++bt)
        c2b(acc[fo][bt], hb[bt][2*fo], hb[bt][2*fo+1]);

    // layer 1 (W1 from LDS A-frags)
    f32x16 a2[4][2];
#pragma unroll
    for (int fo=0; fo<4; ++fo){
      f32x16 bv = load_bias16(b1 + fo*32, half);
      a2[fo][0] = bv; a2[fo][1] = bv;
    }
#pragma unroll
    for (int kt=0; kt<8; ++kt)
#pragma unroll
      for (int fo=0; fo<4; ++fo){
        bhalf8 w = *(const bhalf8*)&wlds[((size_t)(fo*8+kt)*64 + lane)*8];
#pragma unroll
        for (int bt=0; bt<2; ++bt)
          a2[fo][bt] = __builtin_amdgcn_mfma_f32_32x32x16_bf16(w, hb[bt][kt], a2[fo][bt], 0,0,0);
      }

#pragma unroll
    for (int fo=0; fo<4; ++fo)
#pragma unroll
      for (int bt=0; bt<2; ++bt)
        c2b(a2[fo][bt], hb[bt][2*fo], hb[bt][2*fo+1]);

    // layer 2 (W2 frags at offset 32)
#pragma unroll
    for (int fo=0; fo<4; ++fo){
      f32x16 bv = load_bias16(b2 + fo*32, half);
      acc[fo][0] = bv; acc[fo][1] = bv;
    }
#pragma unroll
    for (int kt=0; kt<8; ++kt)
#pragma unroll
      for (int fo=0; fo<4; ++fo){
        bhalf8 w = *(const bhalf8*)&wlds[((size_t)(32 + fo*8+kt)*64 + lane)*8];
#pragma unroll
        for (int bt=0; bt<2; ++bt)
          acc[fo][bt] = __builtin_amdgcn_mfma_f32_32x32x16_bf16(w, hb[bt][kt], acc[fo][bt], 0,0,0);
      }

    // final: val = sigmoid(relu(h3) . wf_i + bf_i)
    float part0 = 0.f, part1 = 0.f;
#pragma unroll
    for (int fo=0; fo<4; ++fo){
      const float* wp = wf + (size_t)i*HD + fo*32;
#pragma unroll
      for (int rg=0; rg<4; ++rg){
        const float4 t = *(const float4*)(wp + rg*8 + half*4);
        float tq[4] = {t.x, t.y, t.z, t.w};
#pragma unroll
        for (int q=0;q<4;++q){
          part0 += fmaxf(acc[fo][0][rg*4+q], 0.f) * tq[q];
          part1 += fmaxf(acc[fo][1][rg*4+q], 0.f) * tq[q];
        }
      }
    }
    float bfv = bf[i];
    float t0 = part0 + __shfl_xor(part0, 32, 64);
    float t1 = part1 + __shfl_xor(part1, 32, 64);
    float val0 = 1.f/(1.f + __expf(-(t0 + bfv)));
    float val1 = 1.f/(1.f + __expf(-(t1 + bfv)));
    if (lane < 32){
      ow[(col)*36 + i]      = val0;
      ow[(32 + col)*36 + i] = val1;
    }
    // make column-i update visible to next iteration's ds_reads (wave-private)
    asm volatile("s_waitcnt lgkmcnt(0)" ::: "memory");
  }

  for (int idx = lane; idx < 64*32; idx += 64){
    int r = idx >> 5, c = idx & 31;
    out[(size_t)(rbase + r)*XD + c] = ow[r*36 + c];
  }
}

extern "C" void kernel_launch(void* const* d_in, const int* in_sizes, int n_in,
                              void* d_out, int out_size, void* d_ws, size_t ws_size,
                              hipStream_t stream){
  (void)in_sizes; (void)n_in; (void)out_size; (void)ws_size;
  const float* x  = (const float*)d_in[0];
  const float* z  = (const float*)d_in[1];
  const float* M  = (const float*)d_in[2];
  const float* Wi = (const float*)d_in[3];
  const float* bi = (const float*)d_in[4];
  const float* wf = (const float*)d_in[5];
  const float* bf = (const float*)d_in[6];
  const float* W1 = (const float*)d_in[7];
  const float* b1 = (const float*)d_in[8];
  const float* W2 = (const float*)d_in[9];
  const float* b2 = (const float*)d_in[10];

  short* wip = (short*)d_ws;                       // 262144 B: packed Wi A-frags
  float* Mt  = (float*)((char*)d_ws + 262144);     // 4096 B: M transposed

  prep_pack<<<dim3(256), dim3(64), 0, stream>>>(Wi, wip);
  prep_mt<<<dim3(1), dim3(1024), 0, stream>>>(M, Mt);

  const int lds_bytes = 65536 + 4*64*36*4;         // 102400
  hipFuncSetAttribute((const void*)genkern, hipFuncAttributeMaxDynamicSharedMemorySize, lds_bytes);
  genkern<<<dim3(256), dim3(256), lds_bytes, stream>>>(
      x, z, bi, wf, bf, W1, b1, W2, b2, wip, Mt, (float*)d_out);
}

// Round 3
// 195.252 us; speedup vs baseline: 1.3022x; 1.3022x over previous
//
#include <hip/hip_runtime.h>
#include <math.h>

#define XD 32
#define HD 128

typedef float f32x16 __attribute__((ext_vector_type(16)));
typedef int v2i __attribute__((ext_vector_type(2)));

#if __has_builtin(__builtin_amdgcn_cvt_pk_fp8_f32)
#define HAVE_CVT_FP8 1
#endif

// ---- scalar f32 -> e4m3fn (RNE), used by prep (and kernel fallback) ----
static __device__ __forceinline__ unsigned char f2e4m3(float f){
  if (!(f==f)) return 0x7F;
  unsigned u = __float_as_uint(f);
  unsigned s = (u>>24)&0x80;
  float a = fabsf(f);
  if (a >= 464.f) return (unsigned char)(s|0x7E);           // clamp to 448
  if (a < 0.0009765625f) return (unsigned char)s;            // < 2^-10 -> 0
  int e = (int)((u>>23)&0xFF) - 127;
  if (e < -6){                                               // subnormal, ulp=2^-9
    int m = (int)rintf(ldexpf(a, 9));
    if (m >= 8) return (unsigned char)(s|0x08);
    return (unsigned char)(s|(unsigned)m);
  }
  int m = (int)rintf(ldexpf(a, 3-e));                        // in [8,16]
  if (m == 16){ ++e; m = 8; }
  if (e > 8) return (unsigned char)(s|0x7E);
  return (unsigned char)(s | (unsigned)((e+7)<<3) | (unsigned)(m-8));
}

template<bool HI>
static __device__ __forceinline__ int cvtpk_fp8(float a, float b, int old){
#ifdef HAVE_CVT_FP8
  return __builtin_amdgcn_cvt_pk_fp8_f32(a, b, old, HI);
#else
  int w = (int)f2e4m3(a) | ((int)f2e4m3(b) << 8);
  return HI ? ((old & 0x0000FFFF) | (w << 16)) : ((old & (int)0xFFFF0000) | w);
#endif
}

// exchange halves: new_x[l] = l<32 ? x[l] : y[l-32]; new_y[l] = l<32 ? x[l+32] : y[l]
static __device__ __forceinline__ void plswap(int &x, int &y){
#if __has_builtin(__builtin_amdgcn_permlane32_swap)
  v2i r = __builtin_amdgcn_permlane32_swap(x, y, false, false);
  x = r[0]; y = r[1];
#else
  unsigned lane = threadIdx.x & 63u;
  int sx = __shfl_xor(x, 32, 64);
  int sy = __shfl_xor(y, 32, 64);
  int nx = (lane < 32) ? x : sy;
  int ny = (lane < 32) ? sx : y;
  x = nx; y = ny;
#endif
}

// One K=16 fp8 B-frag (as long) from a 32x32 f32 C tile, relu applied.
// C: feat=(r&3)+8*(r>>2)+4*half, batch=lane&31.  B: col=lane&31, k=(l>>5)*8+j (byte j).
template<int KT>
static __device__ __forceinline__ long c2b_kt(const f32x16 &c){
  int P0 = cvtpk_fp8<false>(fmaxf(c[8*KT+0],0.f), fmaxf(c[8*KT+1],0.f), 0);
  P0     = cvtpk_fp8<true >(fmaxf(c[8*KT+2],0.f), fmaxf(c[8*KT+3],0.f), P0);
  int P1 = cvtpk_fp8<false>(fmaxf(c[8*KT+4],0.f), fmaxf(c[8*KT+5],0.f), 0);
  P1     = cvtpk_fp8<true >(fmaxf(c[8*KT+6],0.f), fmaxf(c[8*KT+7],0.f), P1);
  plswap(P0, P1);
  return (long)(((unsigned long)(unsigned)P0) | ((unsigned long)(unsigned)P1 << 32));
}

static __device__ __forceinline__ void ld8(const float* __restrict__ p, float* dst){
  float4 a = *(const float4*)p, b = *(const float4*)(p+4);
  dst[0]=a.x; dst[1]=a.y; dst[2]=a.z; dst[3]=a.w;
  dst[4]=b.x; dst[5]=b.y; dst[6]=b.z; dst[7]=b.w;
}

// ---- prep: pack all weights as fp8 A-frags (scaled), fold biases as K-slice ----
// A-frag (32x32x16 fp8): lane l holds row=l&31 (+fo*32), k=(l>>5)*8+j at byte j.
// scale: A_in = 8*Wi (z col at dead diag slot), bias_in = 8*bi;
//        A1 = 8*W1, bias1 = 64*b1; A2 = 8*W2, bias2 = 512*b2.
__global__ void prep(const float* __restrict__ Wi, const float* __restrict__ bi,
                     const float* __restrict__ W1, const float* __restrict__ b1,
                     const float* __restrict__ W2, const float* __restrict__ b2,
                     const float* __restrict__ M,
                     unsigned char* __restrict__ wip, unsigned char* __restrict__ w1p,
                     unsigned char* __restrict__ w2p, float* __restrict__ Mt){
  int b = (int)blockIdx.x;
  int l = (int)threadIdx.x;
  if (b == 456){
#pragma unroll
    for (int t = 0; t < 16; ++t){
      int idx = t*64 + l;
      int i = idx >> 5, k = idx & 31;
      Mt[i*32 + k] = M[k*32 + i];
    }
    return;
  }
  int h = l >> 5, cl = l & 31;
  unsigned char bytes[8];
  unsigned char* dst;
  if (b < 384){
    int i = b / 12, r = b % 12, kt = r >> 2, fo = r & 3;
    int row = fo*32 + cl;
#pragma unroll
    for (int j = 0; j < 8; ++j){
      float v;
      if (kt < 2){
        int k = kt*16 + h*8 + j;
        int src = (k == i) ? XD : k;
        v = 8.f * Wi[((size_t)i*HD + row)*(XD+1) + src];
      } else {
        v = (h==0 && j==0) ? 8.f * bi[(size_t)i*HD + row] : 0.f;
      }
      bytes[j] = f2e4m3(v);
    }
    dst = wip + ((size_t)b*64 + l)*8;
  } else if (b < 420){
    int f = b - 384, kt = f >> 2, fo = f & 3;
    int row = fo*32 + cl;
#pragma unroll
    for (int j = 0; j < 8; ++j){
      float v;
      if (kt < 8) v = 8.f * W1[(size_t)row*HD + kt*16 + h*8 + j];
      else        v = (h==0 && j==0) ? 64.f * b1[row] : 0.f;
      bytes[j] = f2e4m3(v);
    }
    dst = w1p + ((size_t)f*64 + l)*8;
  } else {
    int f = b - 420, kt = f >> 2, fo = f & 3;
    int row = fo*32 + cl;
#pragma unroll
    for (int j = 0; j < 8; ++j){
      float v;
      if (kt < 8) v = 8.f * W2[(size_t)row*HD + kt*16 + h*8 + j];
      else        v = (h==0 && j==0) ? 512.f * b2[row] : 0.f;
      bytes[j] = f2e4m3(v);
    }
    dst = w2p + ((size_t)f*64 + l)*8;
  }
  long v8;
  __builtin_memcpy(&v8, bytes, 8);
  *(long*)dst = v8;
}

// ---- main kernel: 1024 blocks x 64 threads; wave owns 64 rows (bt=2) ----
// All weights resident in VGPR (fp8); out-state in VGPR (half-split); zero LDS.
__global__ void __launch_bounds__(64, 1)
genkern(const float* __restrict__ x, const float* __restrict__ z,
        const float* __restrict__ wf, const float* __restrict__ bf,
        const unsigned char* __restrict__ wip, const unsigned char* __restrict__ w1p,
        const unsigned char* __restrict__ w2p, const float* __restrict__ Mt,
        float* __restrict__ out)
{
  const int lane = (int)threadIdx.x;
  const int half = lane >> 5, col = lane & 31;
  const long rbase = (long)blockIdx.x * 64;

  // resident weight frags
  long w1f[9][4], w2f[9][4];
#pragma unroll
  for (int kt = 0; kt < 9; ++kt)
#pragma unroll
    for (int fo = 0; fo < 4; ++fo){
      w1f[kt][fo] = *(const long*)(w1p + (((size_t)(kt*4+fo))*64 + lane)*8);
      w2f[kt][fo] = *(const long*)(w2p + (((size_t)(kt*4+fo))*64 + lane)*8);
    }
  const long bconst = (half == 0) ? 0x38L : 0L;   // B=1.0 at k_local=0 (e4m3 1.0=0x38)

  // out-state: lane(half h) holds k = kt*16 + h*8 + j at slot kt*8+j, per bt
  float st[2][16];
#pragma unroll
  for (int bt = 0; bt < 2; ++bt)
#pragma unroll
    for (int kt = 0; kt < 2; ++kt)
      ld8(x + (rbase + bt*32 + col)*XD + kt*16 + half*8, &st[bt][kt*8]);

  for (int i = 0; i < XD; ++i){
    // per-step Wi frags: global (L2-hot) -> VGPR
    long wif[3][4];
#pragma unroll
    for (int kt = 0; kt < 3; ++kt)
#pragma unroll
      for (int fo = 0; fo < 4; ++fo)
        wif[kt][fo] = *(const long*)(wip + (((size_t)((i*3+kt)*4+fo))*64 + lane)*8);

    float mtv[2][8];
#pragma unroll
    for (int kt = 0; kt < 2; ++kt)
      ld8(Mt + i*32 + kt*16 + half*8, &mtv[kt][0]);

    float zv[2];
    zv[0] = z[(rbase + col)*XD + i];
    zv[1] = z[(rbase + 32 + col)*XD + i];

    // x_masked B-frags from state (fp8 pack); z injected after
    int xbi[2][2][2];
#pragma unroll
    for (int bt = 0; bt < 2; ++bt)
#pragma unroll
      for (int kt = 0; kt < 2; ++kt)
#pragma unroll
        for (int d = 0; d < 2; ++d){
          float v0 = st[bt][kt*8+4*d+0]*mtv[kt][4*d+0];
          float v1 = st[bt][kt*8+4*d+1]*mtv[kt][4*d+1];
          float v2 = st[bt][kt*8+4*d+2]*mtv[kt][4*d+2];
          float v3 = st[bt][kt*8+4*d+3]*mtv[kt][4*d+3];
          int w = cvtpk_fp8<false>(v0, v1, 0);
          xbi[bt][kt][d] = cvtpk_fp8<true>(v2, v3, w);
        }
    // z byte-splice at k==i (uniform dword select + half-match cndmask)
    const int hmi = (i>>3)&1;
    const bool hm = (half == hmi);
    {
      const int kti = i>>4, di = (i>>2)&1, sh = 8*(i&3);
      const int msk = ~(0xFF << sh);
#pragma unroll
      for (int bt = 0; bt < 2; ++bt){
        int pz = cvtpk_fp8<false>(zv[bt], 0.f, 0) & 0xFF;
        int ins = pz << sh;
#pragma unroll
        for (int kt = 0; kt < 2; ++kt)
#pragma unroll
          for (int d = 0; d < 2; ++d)
            if (kt == kti && d == di){
              int mod = (xbi[bt][kt][d] & msk) | ins;
              xbi[bt][kt][d] = hm ? mod : xbi[bt][kt][d];
            }
      }
    }
    long xb[2][2];
#pragma unroll
    for (int bt = 0; bt < 2; ++bt)
#pragma unroll
      for (int kt = 0; kt < 2; ++kt)
        xb[bt][kt] = (long)(((unsigned long)(unsigned)xbi[bt][kt][0]) |
                            ((unsigned long)(unsigned)xbi[bt][kt][1] << 32));

    // input layer: K=48 (2 x xm + bias slice)
    f32x16 acc[4][2];
#pragma unroll
    for (int fo = 0; fo < 4; ++fo)
#pragma unroll
      for (int bt = 0; bt < 2; ++bt)
#pragma unroll
        for (int q = 0; q < 16; ++q) acc[fo][bt][q] = 0.f;
#pragma unroll
    for (int kt = 0; kt < 3; ++kt)
#pragma unroll
      for (int fo = 0; fo < 4; ++fo)
#pragma unroll
        for (int bt = 0; bt < 2; ++bt){
          long bo = (kt < 2) ? xb[bt][kt] : bconst;
          acc[fo][bt] = __builtin_amdgcn_mfma_f32_32x32x16_fp8_fp8(wif[kt][fo], bo, acc[fo][bt], 0,0,0);
        }

    // h1 -> fp8 B-frags
    long hb[2][8];
#pragma unroll
    for (int fo = 0; fo < 4; ++fo)
#pragma unroll
      for (int bt = 0; bt < 2; ++bt){
        hb[bt][fo*2+0] = c2b_kt<0>(acc[fo][bt]);
        hb[bt][fo*2+1] = c2b_kt<1>(acc[fo][bt]);
      }

    // layer 1: K=144 (8 x h + bias)
    f32x16 a2[4][2];
#pragma unroll
    for (int fo = 0; fo < 4; ++fo)
#pragma unroll
      for (int bt = 0; bt < 2; ++bt)
#pragma unroll
        for (int q = 0; q < 16; ++q) a2[fo][bt][q] = 0.f;
#pragma unroll
    for (int kt = 0; kt < 9; ++kt)
#pragma unroll
      for (int fo = 0; fo < 4; ++fo)
#pragma unroll
        for (int bt = 0; bt < 2; ++bt){
          long bo = (kt < 8) ? hb[bt][kt] : bconst;
          a2[fo][bt] = __builtin_amdgcn_mfma_f32_32x32x16_fp8_fp8(w1f[kt][fo], bo, a2[fo][bt], 0,0,0);
        }
#pragma unroll
    for (int fo = 0; fo < 4; ++fo)
#pragma unroll
      for (int bt = 0; bt < 2; ++bt){
        hb[bt][fo*2+0] = c2b_kt<0>(a2[fo][bt]);
        hb[bt][fo*2+1] = c2b_kt<1>(a2[fo][bt]);
      }

    // layer 2 into acc
#pragma unroll
    for (int fo = 0; fo < 4; ++fo)
#pragma unroll
      for (int bt = 0; bt < 2; ++bt)
#pragma unroll
        for (int q = 0; q < 16; ++q) acc[fo][bt][q] = 0.f;
#pragma unroll
    for (int kt = 0; kt < 9; ++kt)
#pragma unroll
      for (int fo = 0; fo < 4; ++fo)
#pragma unroll
        for (int bt = 0; bt < 2; ++bt){
          long bo = (kt < 8) ? hb[bt][kt] : bconst;
          acc[fo][bt] = __builtin_amdgcn_mfma_f32_32x32x16_fp8_fp8(w2f[kt][fo], bo, acc[fo][bt], 0,0,0);
        }

    // epilogue: val = sigmoid((relu(h3') . wf)/512 + bf)   (h3' is 512x-scaled)
    float part0 = 0.f, part1 = 0.f;
#pragma unroll
    for (int fo = 0; fo < 4; ++fo){
      const float* wp = wf + (size_t)i*HD + fo*32;
#pragma unroll
      for (int rg = 0; rg < 4; ++rg){
        const float4 t = *(const float4*)(wp + rg*8 + half*4);
        float tq[4] = {t.x, t.y, t.z, t.w};
#pragma unroll
        for (int q = 0; q < 4; ++q){
          part0 += fmaxf(acc[fo][0][rg*4+q], 0.f) * tq[q];
          part1 += fmaxf(acc[fo][1][rg*4+q], 0.f) * tq[q];
        }
      }
    }
    float bfv = bf[i];
    float t0 = part0 + __shfl_xor(part0, 32, 64);
    float t1 = part1 + __shfl_xor(part1, 32, 64);
    float val0 = 1.f/(1.f + __expf(-(t0*(1.f/512.f) + bfv)));
    float val1 = 1.f/(1.f + __expf(-(t1*(1.f/512.f) + bfv)));

    // state update: column i lives at slot (i>>4)*8+(i&7) on half (i>>3)&1
    const int slot_i = ((i>>4)<<3) | (i&7);
#pragma unroll
    for (int s = 0; s < 16; ++s)
      if (s == slot_i){
        st[0][s] = hm ? val0 : st[0][s];
        st[1][s] = hm ? val1 : st[1][s];
      }
  }

  // write out
#pragma unroll
  for (int bt = 0; bt < 2; ++bt)
#pragma unroll
    for (int kt = 0; kt < 2; ++kt){
      float* p = out + (rbase + bt*32 + col)*XD + kt*16 + half*8;
      float4 a, b;
      a.x = st[bt][kt*8+0]; a.y = st[bt][kt*8+1]; a.z = st[bt][kt*8+2]; a.w = st[bt][kt*8+3];
      b.x = st[bt][kt*8+4]; b.y = st[bt][kt*8+5]; b.z = st[bt][kt*8+6]; b.w = st[bt][kt*8+7];
      *(float4*)p = a;
      *(float4*)(p+4) = b;
    }
}

extern "C" void kernel_launch(void* const* d_in, const int* in_sizes, int n_in,
                              void* d_out, int out_size, void* d_ws, size_t ws_size,
                              hipStream_t stream){
  (void)in_sizes; (void)n_in; (void)out_size; (void)ws_size;
  const float* x  = (const float*)d_in[0];
  const float* z  = (const float*)d_in[1];
  const float* M  = (const float*)d_in[2];
  const float* Wi = (const float*)d_in[3];
  const float* bi = (const float*)d_in[4];
  const float* wf = (const float*)d_in[5];
  const float* bf = (const float*)d_in[6];
  const float* W1 = (const float*)d_in[7];
  const float* b1 = (const float*)d_in[8];
  const float* W2 = (const float*)d_in[9];
  const float* b2 = (const float*)d_in[10];

  unsigned char* wip = (unsigned char*)d_ws;            // 384*512 = 196608
  unsigned char* w1p = wip + 196608;                    // 36*512 = 18432
  unsigned char* w2p = w1p + 18432;                     // 18432
  float*         Mt  = (float*)(w2p + 18432);           // 4096

  prep<<<dim3(457), dim3(64), 0, stream>>>(Wi, bi, W1, b1, W2, b2, M, wip, w1p, w2p, Mt);
  genkern<<<dim3(1024), dim3(64), 0, stream>>>(x, z, wf, bf, wip, w1p, w2p, Mt, (float*)d_out);
}